// Round 8
// baseline (257.107 us; speedup 1.0000x reference)
//
#include <hip/hip_runtime.h>

typedef unsigned int UI;
typedef unsigned short u16;

typedef short short8 __attribute__((ext_vector_type(8)));
typedef float floatx4 __attribute__((ext_vector_type(4)));
typedef unsigned short ushort8 __attribute__((ext_vector_type(8)));

__device__ __forceinline__ float bf2f(u16 u) {
  return __uint_as_float(((UI)u) << 16);
}
__device__ __forceinline__ u16 f2bf(float x) {  // RNE
  UI u = __float_as_uint(x);
  u += 0x7fffu + ((u >> 16) & 1u);
  return (u16)(u >> 16);
}
__device__ __forceinline__ float fsigmoid(float v) {
  float e = __builtin_amdgcn_exp2f(-1.44269504089f * v);
  return __builtin_amdgcn_rcpf(1.0f + e);
}
__device__ __forceinline__ float fsilu(float v) { return v * fsigmoid(v); }

// ---------------- K1: layernorm h/x + weight transposes ----------------
__global__ __launch_bounds__(256) void k1_ln(
    const float* __restrict__ h, const float* __restrict__ x,
    const float* __restrict__ lnh_w, const float* __restrict__ lnh_b,
    const float* __restrict__ lnx_w, const float* __restrict__ lnx_b,
    const float* __restrict__ edg1_w, const float* __restrict__ cor1_w,
    const float* __restrict__ node1_w, const float* __restrict__ node2_w,
    float* __restrict__ hln, float* __restrict__ xln,
    float* __restrict__ e1T, float* __restrict__ c1T,
    float* __restrict__ n1T, float* __restrict__ n2T) {
  __shared__ float tile[32][33];
  const int bx = blockIdx.x, tid = threadIdx.x;
  if (bx < 128) {
    const int wv = tid >> 6, lane = tid & 63;
#pragma unroll 1
    for (int s = 0; s < 2; ++s) {
      const int n = bx * 8 + wv * 2 + s;
      const float* hp = h + n * 128;
      float v0 = hp[lane], v1 = hp[lane + 64];
      float sum = v0 + v1;
#pragma unroll
      for (int m = 1; m < 64; m <<= 1) sum += __shfl_xor(sum, m);
      float mean = sum * 0.0078125f;
      float d0 = v0 - mean, d1 = v1 - mean;
      float vs = d0 * d0 + d1 * d1;
#pragma unroll
      for (int m = 1; m < 64; m <<= 1) vs += __shfl_xor(vs, m);
      float rstd = __builtin_amdgcn_rcpf(__builtin_amdgcn_sqrtf(vs * 0.0078125f + 1e-5f));
      hln[n * 128 + lane]      = d0 * rstd * lnh_w[lane] + lnh_b[lane];
      hln[n * 128 + lane + 64] = d1 * rstd * lnh_w[lane + 64] + lnh_b[lane + 64];
      if (lane == 0) {
        float a = x[n * 3], b2 = x[n * 3 + 1], c = x[n * 3 + 2];
        float m3 = (a + b2 + c) * (1.f / 3.f);
        float va = (a - m3) * (a - m3) + (b2 - m3) * (b2 - m3) + (c - m3) * (c - m3);
        float rs = __builtin_amdgcn_rcpf(__builtin_amdgcn_sqrtf(va * (1.f / 3.f) + 1e-5f));
        xln[n * 3 + 0] = (a - m3) * rs * lnx_w[0] + lnx_b[0];
        xln[n * 3 + 1] = (b2 - m3) * rs * lnx_w[1] + lnx_b[1];
        xln[n * 3 + 2] = (c - m3) * rs * lnx_w[2] + lnx_b[2];
      }
    }
    return;
  }
  int tb = bx - 128;
  const float* src; float* dst; int ld, ntc;
  if (tb < 32)      { src = edg1_w;  dst = e1T; ld = 258; ntc = 8; }
  else if (tb < 64) { src = cor1_w;  dst = c1T; ld = 258; ntc = 8; tb -= 32; }
  else if (tb < 96) { src = node1_w; dst = n1T; ld = 256; ntc = 8; tb -= 64; }
  else              { src = node2_w; dst = n2T; ld = 128; ntc = 4; tb -= 96; }
  const int r0 = (tb / ntc) * 32, c0 = (tb % ntc) * 32;
  const int tx = tid & 31, ty = tid >> 5;
#pragma unroll
  for (int p = 0; p < 4; ++p)
    tile[ty + p * 8][tx] = src[(r0 + ty + p * 8) * ld + c0 + tx];
  __syncthreads();
#pragma unroll
  for (int p = 0; p < 4; ++p)
    dst[(c0 + ty + p * 8) * 128 + r0 + tx] = tile[tx][ty + p * 8];
}

// ---------------- K2: per-node pre-GEMMs + weight repacks ----------------
// w2e/w2c are written in K3's conflict-free LDS order: 16B granule
// G = nt*256 + ks*64 + ch*16 + il holds w2[nt*16+il][ks*32+ch*8 .. +8].
// In K3, lane (il,ch) then reads granule ks*64 + lane -> linear, 0-conflict.
__global__ __launch_bounds__(256, 2) void k2_pre(
    const float* __restrict__ hln,
    const float* __restrict__ e1T, const float* __restrict__ edg1_b,
    const float* __restrict__ c1T, const float* __restrict__ cor1_b,
    const float* __restrict__ edg1_w, const float* __restrict__ cor1_w,
    const float* __restrict__ edg2_w, const float* __restrict__ cor2_w,
    u16* __restrict__ peA, u16* __restrict__ peB,
    u16* __restrict__ pcA, u16* __restrict__ pcB,
    u16* __restrict__ w2e, u16* __restrict__ w2c,
    float* __restrict__ wdwr) {
  const int tid = threadIdx.x;
  const int bx = blockIdx.x;
  if (bx >= 256) {
    const float* src = (bx == 256) ? edg2_w : cor2_w;
    u16* dst = (bx == 256) ? w2e : w2c;
    for (int idx = tid; idx < 16384; idx += 256) {
      int f = idx >> 7, k = idx & 127;
      int nt = f >> 4, il = f & 15, ks = k >> 5, ch = (k >> 3) & 3, e = k & 7;
      dst[(nt * 256 + ks * 64 + ch * 16 + il) * 8 + e] = f2bf(src[idx]);
    }
    const float* w1 = (bx == 256) ? edg1_w : cor1_w;
    float* wvv = wdwr + ((bx == 256) ? 0 : 256);
    if (tid < 128) wvv[tid] = w1[tid * 258 + 256];           // wd (dsq col)
    else           wvv[tid] = w1[(tid - 128) * 258 + 257];   // wr (r0 col)
    return;
  }
  __shared__ __align__(16) float hl[16][132];
  const int arr = bx >> 6;
  const int nb = bx & 63;
  const int n0 = nb * 16;
  for (int idx = tid; idx < 2048; idx += 256) {
    int r = idx >> 7, k = idx & 127;
    hl[r][k] = hln[(n0 + r) * 128 + k];
  }
  __syncthreads();
  const int f = tid & 127, nh = tid >> 7;
  const float* w1T = (arr < 2) ? e1T : c1T;
  const int off = (arr & 1) ? 128 : 0;
  u16* dst = (arr == 0) ? peA : (arr == 1) ? peB : (arr == 2) ? pcA : pcB;
  float bias = 0.f;
  if (arr == 0) bias = edg1_b[f];
  if (arr == 2) bias = cor1_b[f];
  float wreg[128];
#pragma unroll
  for (int t = 0; t < 128; ++t) wreg[t] = w1T[(off + t) * 128 + f];  // coalesced
#pragma unroll 1
  for (int s = 0; s < 8; ++s) {
    int nl = nh * 8 + s;
    float acc = bias;
#pragma unroll
    for (int t = 0; t < 64; ++t) {
      float2 iv = *(const float2*)&hl[nl][t * 2];
      acc += wreg[2 * t] * iv.x + wreg[2 * t + 1] * iv.y;
    }
    dst[(n0 + nl) * 128 + f] = f2bf(acc);
  }
}

// ---------------- K3: fused per-pair edge/coord MLPs (16x16x32 MFMA) -------
// grid 1024: path = bx>>9; per wg: 16 i's x 32 j's, 4 waves; wave w: j=w*8+g.
// REGISTER HISTORY (hard constraint; with MFMA the per-wave budget splits in
// half arch/acc):
//   (256,3): 84 arch -> 1.14 GB scratch spill, 337us           (R4)
//   (256,2) + FULL ks unroll: 350-530 MB spill, 203-278us      (R5/R6)
//   (256,2) + `#pragma unroll 1` ks loop: 88 VGPR, no spill,
//     96us, VALUBusy 45% / MfmaUtil 7.3% (issue-ratio-verified) (R7)
// R8: cut VALU (v_cvt_pk_bf16_f32 replaces manual f2bf+pack, ~40->4 ops/ks)
//     and LDS conflicts (sW/sA granule layouts: lane reads granule==lane;
//     R7 counter was 4.7M conflict-cycles).
__global__ __launch_bounds__(256, 2) void k3_pair(
    const float* __restrict__ x, const float* __restrict__ x0,
    const u16* __restrict__ peA, const u16* __restrict__ peB,
    const u16* __restrict__ pcA, const u16* __restrict__ pcB,
    const u16* __restrict__ w2e, const u16* __restrict__ w2c,
    const float* __restrict__ wdwr,
    const float* __restrict__ b2e, const float* __restrict__ b2c,
    const float* __restrict__ edgi_w, const float* __restrict__ edgi_b,
    const float* __restrict__ cor3_w, const float* __restrict__ cor3_b,
    float* __restrict__ cw_t, float* __restrict__ partial) {
  __shared__ __align__(16) u16 sW[2048 * 8];    // 32768 B, granule layout
  __shared__ __align__(16) u16 sA[256 * 8];     // 4096 B, granule layout
  __shared__ __align__(16) u16 sB[32 * 136];    // 8704 B, row-major (bcast reads)
  __shared__ __align__(16) float swd[128];
  __shared__ __align__(16) float swr[128];
  __shared__ float sxi[16][4], sxj[32][4], sx0i[16][4], sx0j[32][4];
  __shared__ __align__(16) float sagg[16][128]; // 8192 B (edge agg accumulator)

  const int tid = threadIdx.x;
  const int bx = blockIdx.x;
  const int path = bx >> 9;
  const int rem = bx & 511;
  const int b = rem >> 7;
  const int ib = (rem >> 3) & 15;
  const int jc = rem & 7;
  const int i0 = ib * 16, j0 = jc * 32;

  const u16* pA = path ? pcA : peA;
  const u16* pB = path ? pcB : peB;
  const u16* w2 = path ? w2c : w2e;
  const float* wdp = wdwr + path * 256;
  const float* b2 = path ? b2c : b2e;
  const float* w3 = path ? cor3_w : edgi_w;
  const float w3b = path ? cor3_b[0] : edgi_b[0];

  float* pslot = partial + ((b * 16 + ib) * 8 + jc) * 2048;

  {
    // sW: already in granule order (K2 pre-transformed) -> linear copy
    const uint4* src = (const uint4*)w2;
    uint4* dst = (uint4*)sW;
    for (int d = tid; d < 2048; d += 256) dst[d] = src[d];
    // sA: granule G = ks*64 + ch*16 + il  <-  src granule il*16 + ks*4 + ch
    {
      const uint4* sa_src = (const uint4*)(pA + (b * 256 + i0) * 128);
      int il = tid & 15, ch = (tid >> 4) & 3, ks = tid >> 6;
      ((uint4*)sA)[tid] = sa_src[il * 16 + ks * 4 + ch];
    }
    const UI* sb_src = (const UI*)(pB + (b * 256 + j0) * 128);
    UI* sb_dst = (UI*)sB;
    for (int d = tid; d < 2048; d += 256) {
      int r = d >> 6, c = d & 63;
      sb_dst[r * 68 + c] = sb_src[d];
    }
    if (tid < 128) swd[tid] = wdp[tid];
    else           swr[tid - 128] = wdp[tid];
    if (tid < 64) {
      int r = tid >> 2, d = tid & 3;
      sxi[r][d]  = (d < 3) ? x[(b * 256 + i0 + r) * 3 + d] : 0.f;
      sx0i[r][d] = (d < 3) ? x0[(b * 256 + i0 + r) * 3 + d] : 0.f;
    }
    if (tid < 128) {
      int r = tid >> 2, d = tid & 3;
      sxj[r][d]  = (d < 3) ? x[(b * 256 + j0 + r) * 3 + d] : 0.f;
      sx0j[r][d] = (d < 3) ? x0[(b * 256 + j0 + r) * 3 + d] : 0.f;
    }
    float* ag = (float*)sagg;
    for (int d = tid; d < 2048; d += 256) ag[d] = 0.f;
  }
  __syncthreads();

  const int lane = tid & 63;
  const int w = tid >> 6;
  const int il = lane & 15;   // MFMA row (A) / col (B, C/D)
  const int ch = lane >> 4;   // k-chunk (A/B) / C-row group

  float wv[8], bv[8];
#pragma unroll
  for (int nt = 0; nt < 8; ++nt) {
    wv[nt] = w3[nt * 16 + il];
    bv[nt] = b2[nt * 16 + il];
  }

  float aggv[8][4];
#pragma unroll
  for (int nt = 0; nt < 8; ++nt)
#pragma unroll
    for (int q = 0; q < 4; ++q) aggv[nt][q] = 0.f;

#pragma unroll 1
  for (int g = 0; g < 8; ++g) {
    const int jl = w * 8 + g;  // this wave's j within the block
    float d0 = sxi[il][0] - sxj[jl][0];
    float d1 = sxi[il][1] - sxj[jl][1];
    float d2 = sxi[il][2] - sxj[jl][2];
    const float dsq = d0 * d0 + d1 * d1 + d2 * d2;
    float e0 = sx0i[il][0] - sx0j[jl][0];
    float e1 = sx0i[il][1] - sx0j[jl][1];
    float e2 = sx0i[il][2] - sx0j[jl][2];
    float q2 = e0 * e0 + e1 * e1 + e2 * e2;
    const float r0v = (q2 > 0.f) ? __builtin_amdgcn_sqrtf(q2) : 0.f;

    floatx4 acc[8];
#pragma unroll
    for (int nt = 0; nt < 8; ++nt)
#pragma unroll
      for (int q = 0; q < 4; ++q) acc[nt][q] = 0.f;

#pragma unroll 1
    for (int ks = 0; ks < 4; ++ks) {
      const int f0 = ks * 32 + ch * 8;
      union { float4 v[2]; float a[8]; } wd8, wr8;
      wd8.v[0] = *(const float4*)&swd[f0];
      wd8.v[1] = *(const float4*)&swd[f0 + 4];
      wr8.v[0] = *(const float4*)&swr[f0];
      wr8.v[1] = *(const float4*)&swr[f0 + 4];
      ushort8 a8 = *(const ushort8*)&sA[(ks * 64 + lane) * 8];      // linear
      ushort8 b8 = *(const ushort8*)&sB[jl * 136 + f0];             // bcast
      union { UI w[4]; short8 s; } afu;
#pragma unroll
      for (int e2 = 0; e2 < 4; ++e2) {
        float s0 = fsilu(bf2f((u16)a8[2 * e2]) + bf2f((u16)b8[2 * e2]) +
                         dsq * wd8.a[2 * e2] + r0v * wr8.a[2 * e2]);
        float s1 = fsilu(bf2f((u16)a8[2 * e2 + 1]) + bf2f((u16)b8[2 * e2 + 1]) +
                         dsq * wd8.a[2 * e2 + 1] + r0v * wr8.a[2 * e2 + 1]);
        asm("v_cvt_pk_bf16_f32 %0, %1, %2" : "=v"(afu.w[e2]) : "v"(s0), "v"(s1));
      }
#pragma unroll
      for (int nt = 0; nt < 8; ++nt) {
        short8 bfr = *(const short8*)&sW[(nt * 256 + ks * 64 + lane) * 8];  // linear
        acc[nt] = __builtin_amdgcn_mfma_f32_16x16x32_bf16(afu.s, bfr, acc[nt], 0, 0, 0);
      }
    }
    // epilogue: silu+bias, inner product with w3, 16-lane butterfly reduce
    float p[4] = {0.f, 0.f, 0.f, 0.f};
#pragma unroll
    for (int nt = 0; nt < 8; ++nt) {
#pragma unroll
      for (int q = 0; q < 4; ++q) {
        float s = fsilu(acc[nt][q] + bv[nt]);
        acc[nt][q] = s;
        p[q] += s * wv[nt];
      }
    }
#pragma unroll
    for (int m = 1; m < 16; m <<= 1) {
#pragma unroll
      for (int q = 0; q < 4; ++q) p[q] += __shfl_xor(p[q], m);
    }
    const int jg = j0 + jl;
    if (path == 0) {
#pragma unroll
      for (int q = 0; q < 4; ++q) {
        int ig = i0 + ch * 4 + q;
        float ev = (ig == jg) ? 0.f : fsigmoid(p[q] + w3b);
#pragma unroll
        for (int nt = 0; nt < 8; ++nt) aggv[nt][q] += ev * acc[nt][q];
      }
    } else {
      if (il == 0) {
        float4 v;
        v.x = p[0] + w3b; v.y = p[1] + w3b; v.z = p[2] + w3b; v.w = p[3] + w3b;
        *(float4*)&cw_t[(b * 256 + jg) * 256 + i0 + ch * 4] = v;
      }
    }
  }
  if (path == 0) {
    // single merge pass: 4 waves x 32 LDS atomics/lane, then copy out
#pragma unroll
    for (int nt = 0; nt < 8; ++nt)
#pragma unroll
      for (int q = 0; q < 4; ++q)
        atomicAdd(&sagg[ch * 4 + q][nt * 16 + il], aggv[nt][q]);
    __syncthreads();
    const float* ag = (const float*)sagg;
    for (int d = tid; d < 2048; d += 256) pslot[d] = ag[d];
  }
}

// ---------------- K4: node MLP + residual ----------------
__global__ __launch_bounds__(256, 2) void k4_node(
    const float* __restrict__ hln, const float* __restrict__ partial,
    const float* __restrict__ n1T, const float* __restrict__ n1b,
    const float* __restrict__ n2T, const float* __restrict__ n2b,
    float* __restrict__ out) {
  __shared__ __align__(16) float sin_[4][260];
  __shared__ __align__(16) float snu[4][132];
  const int tid = threadIdx.x;
  const int n0 = blockIdx.x * 4;
  for (int idx = tid; idx < 512; idx += 256) {
    int s = idx >> 7, k = idx & 127;
    sin_[s][k] = hln[(n0 + s) * 128 + k];
  }
  for (int idx = tid; idx < 512; idx += 256) {
    int s = idx >> 7, f = idx & 127;
    int n = n0 + s, b = n >> 8, i = n & 255;
    const float* pp = partial + ((b * 16 + (i >> 4)) * 8) * 2048 + (i & 15) * 128 + f;
    float a = 0.f;
#pragma unroll
    for (int j = 0; j < 8; ++j) a += pp[j * 2048];
    sin_[s][128 + f] = a;
  }
  __syncthreads();
  const int f = tid & 127, sh = tid >> 7;
  UI w1r[128];
#pragma unroll
  for (int t = 0; t < 128; ++t) {
    float wa = n1T[(t * 2) * 128 + f];      // coalesced (k-major)
    float wb = n1T[(t * 2 + 1) * 128 + f];
    w1r[t] = (UI)f2bf(wa) | ((UI)f2bf(wb) << 16);
  }
#pragma unroll 1
  for (int t2 = 0; t2 < 2; ++t2) {
    int s = sh * 2 + t2;
    float acc = n1b[f];
#pragma unroll
    for (int t = 0; t < 128; ++t) {
      UI wp = w1r[t];
      float2 iv = *(const float2*)&sin_[s][t * 2];
      acc += iv.x * bf2f((u16)(wp & 0xffffu)) + iv.y * bf2f((u16)(wp >> 16));
    }
    snu[s][f] = fsilu(acc);
  }
  __syncthreads();
  UI w2r[64];
#pragma unroll
  for (int t = 0; t < 64; ++t) {
    float wa = n2T[(t * 2) * 128 + f];
    float wb = n2T[(t * 2 + 1) * 128 + f];
    w2r[t] = (UI)f2bf(wa) | ((UI)f2bf(wb) << 16);
  }
#pragma unroll 1
  for (int t2 = 0; t2 < 2; ++t2) {
    int s = sh * 2 + t2;
    float acc = n2b[f];
#pragma unroll
    for (int t = 0; t < 64; ++t) {
      UI wp = w2r[t];
      float2 iv = *(const float2*)&snu[s][t * 2];
      acc += iv.x * bf2f((u16)(wp & 0xffffu)) + iv.y * bf2f((u16)(wp >> 16));
    }
    out[3072 + (n0 + s) * 128 + f] = sin_[s][f] + acc;  // h_ln + node2(nu)
  }
}

// ---------------- K5: coordinate update ----------------
__global__ __launch_bounds__(256) void k5_x(
    const float* __restrict__ x, const float* __restrict__ xln,
    const float* __restrict__ cw_t, float* __restrict__ out) {
  const int wv = threadIdx.x >> 6, lane = threadIdx.x & 63;
  const int n = blockIdx.x * 4 + wv;
  const int b = n >> 8, i = n & 255;
  const float xi0 = x[n * 3 + 0], xi1 = x[n * 3 + 1], xi2 = x[n * 3 + 2];
  float s0 = 0.f, s1 = 0.f, s2 = 0.f;
#pragma unroll
  for (int t = 0; t < 4; ++t) {
    int j = t * 64 + lane;
    const float* xj = x + (b * 256 + j) * 3;
    float d0 = xi0 - xj[0], d1 = xi1 - xj[1], d2 = xi2 - xj[2];
    float q = d0 * d0 + d1 * d1 + d2 * d2;
    float r = (q > 0.f) ? __builtin_amdgcn_sqrtf(q) : 0.f;
    float cw = cw_t[(b * 256 + j) * 256 + i];
    float sc = cw * __builtin_amdgcn_rcpf(r + 1.f);
    s0 += sc * d0; s1 += sc * d1; s2 += sc * d2;
  }
#pragma unroll
  for (int m = 1; m < 64; m <<= 1) {
    s0 += __shfl_xor(s0, m);
    s1 += __shfl_xor(s1, m);
    s2 += __shfl_xor(s2, m);
  }
  if (lane == 0) {
    out[n * 3 + 0] = xln[n * 3 + 0] + s0;
    out[n * 3 + 1] = xln[n * 3 + 1] + s1;
    out[n * 3 + 2] = xln[n * 3 + 2] + s2;
  }
}

extern "C" void kernel_launch(void* const* d_in, const int* in_sizes, int n_in,
                              void* d_out, int out_size, void* d_ws, size_t ws_size,
                              hipStream_t stream) {
  (void)in_sizes; (void)n_in; (void)out_size; (void)ws_size;
  const float* x      = (const float*)d_in[0];
  const float* h      = (const float*)d_in[1];
  const float* x0     = (const float*)d_in[2];
  const float* lnh_w  = (const float*)d_in[3];
  const float* lnh_b  = (const float*)d_in[4];
  const float* lnx_w  = (const float*)d_in[5];
  const float* lnx_b  = (const float*)d_in[6];
  const float* edg1_w = (const float*)d_in[7];
  const float* edg1_b = (const float*)d_in[8];
  const float* edg2_w = (const float*)d_in[9];
  const float* edg2_b = (const float*)d_in[10];
  const float* edgi_w = (const float*)d_in[11];
  const float* edgi_b = (const float*)d_in[12];
  const float* node1_w= (const float*)d_in[13];
  const float* node1_b= (const float*)d_in[14];
  const float* node2_w= (const float*)d_in[15];
  const float* node2_b= (const float*)d_in[16];
  const float* cor1_w = (const float*)d_in[17];
  const float* cor1_b = (const float*)d_in[18];
  const float* cor2_w = (const float*)d_in[19];
  const float* cor2_b = (const float*)d_in[20];
  const float* cor3_w = (const float*)d_in[21];
  const float* cor3_b = (const float*)d_in[22];

  char* ws = (char*)d_ws;
  float* hln  = (float*)(ws);                 // 1024*128 f32 = 512 KB
  float* xln  = (float*)(ws + 524288);        // 1024*3 f32
  u16* peA    = (u16*)(ws + 536576);          // [1024][128] bf16
  u16* peB    = (u16*)(ws + 798720);
  u16* pcA    = (u16*)(ws + 1060864);
  u16* pcB    = (u16*)(ws + 1323008);
  u16* w2e    = (u16*)(ws + 1585152);         // [2048 granules][8] bf16 = 32 KB
  u16* w2c    = (u16*)(ws + 1619968);
  float* wdwr = (float*)(ws + 1654784);       // [4][128] f32
  float* cw_t = (float*)(ws + 1656832);       // [4][256 j][256 i] f32 = 1 MB
  float* partial = (float*)(ws + 2705408);    // [4][16][8][16][128] f32 = 4 MB
  float* e1T  = (float*)(ws + 6899712);       // [256][128] f32 = 128 KB
  float* c1T  = (float*)(ws + 7030784);       // [256][128] f32
  float* n1T  = (float*)(ws + 7161856);       // [256][128] f32
  float* n2T  = (float*)(ws + 7292928);       // [128][128] f32 = 64 KB
  float* out  = (float*)d_out;

  hipLaunchKernelGGL(k1_ln, dim3(240), dim3(256), 0, stream,
                     h, x, lnh_w, lnh_b, lnx_w, lnx_b,
                     edg1_w, cor1_w, node1_w, node2_w,
                     hln, xln, e1T, c1T, n1T, n2T);
  hipLaunchKernelGGL(k2_pre, dim3(258), dim3(256), 0, stream,
                     hln, e1T, edg1_b, c1T, cor1_b, edg1_w, cor1_w,
                     edg2_w, cor2_w, peA, peB, pcA, pcB, w2e, w2c, wdwr);
  hipLaunchKernelGGL(k3_pair, dim3(1024), dim3(256), 0, stream,
                     x, x0, peA, peB, pcA, pcB, w2e, w2c, wdwr,
                     edg2_b, cor2_b, edgi_w, edgi_b, cor3_w, cor3_b, cw_t, partial);
  hipLaunchKernelGGL(k4_node, dim3(256), dim3(256), 0, stream,
                     hln, partial, n1T, node1_b, n2T, node2_b, out);
  hipLaunchKernelGGL(k5_x, dim3(256), dim3(256), 0, stream,
                     x, xln, cw_t, out);
}

// Round 9
// 236.617 us; speedup vs baseline: 1.0866x; 1.0866x over previous
//
#include <hip/hip_runtime.h>

typedef unsigned int UI;
typedef unsigned short u16;

typedef short short8 __attribute__((ext_vector_type(8)));
typedef float floatx4 __attribute__((ext_vector_type(4)));
typedef unsigned short ushort8 __attribute__((ext_vector_type(8)));

__device__ __forceinline__ float bf2f(u16 u) {
  return __uint_as_float(((UI)u) << 16);
}
__device__ __forceinline__ u16 f2bf(float x) {  // RNE
  UI u = __float_as_uint(x);
  u += 0x7fffu + ((u >> 16) & 1u);
  return (u16)(u >> 16);
}
__device__ __forceinline__ float fsigmoid(float v) {
  float e = __builtin_amdgcn_exp2f(-1.44269504089f * v);
  return __builtin_amdgcn_rcpf(1.0f + e);
}
__device__ __forceinline__ float fsilu(float v) { return v * fsigmoid(v); }

// ---------------- K1: layernorm h/x + weight transposes ----------------
__global__ __launch_bounds__(256) void k1_ln(
    const float* __restrict__ h, const float* __restrict__ x,
    const float* __restrict__ lnh_w, const float* __restrict__ lnh_b,
    const float* __restrict__ lnx_w, const float* __restrict__ lnx_b,
    const float* __restrict__ edg1_w, const float* __restrict__ cor1_w,
    const float* __restrict__ node1_w, const float* __restrict__ node2_w,
    float* __restrict__ hln, float* __restrict__ xln,
    float* __restrict__ e1T, float* __restrict__ c1T,
    float* __restrict__ n1T, float* __restrict__ n2T) {
  __shared__ float tile[32][33];
  const int bx = blockIdx.x, tid = threadIdx.x;
  if (bx < 128) {
    const int wv = tid >> 6, lane = tid & 63;
#pragma unroll 1
    for (int s = 0; s < 2; ++s) {
      const int n = bx * 8 + wv * 2 + s;
      const float* hp = h + n * 128;
      float v0 = hp[lane], v1 = hp[lane + 64];
      float sum = v0 + v1;
#pragma unroll
      for (int m = 1; m < 64; m <<= 1) sum += __shfl_xor(sum, m);
      float mean = sum * 0.0078125f;
      float d0 = v0 - mean, d1 = v1 - mean;
      float vs = d0 * d0 + d1 * d1;
#pragma unroll
      for (int m = 1; m < 64; m <<= 1) vs += __shfl_xor(vs, m);
      float rstd = __builtin_amdgcn_rcpf(__builtin_amdgcn_sqrtf(vs * 0.0078125f + 1e-5f));
      hln[n * 128 + lane]      = d0 * rstd * lnh_w[lane] + lnh_b[lane];
      hln[n * 128 + lane + 64] = d1 * rstd * lnh_w[lane + 64] + lnh_b[lane + 64];
      if (lane == 0) {
        float a = x[n * 3], b2 = x[n * 3 + 1], c = x[n * 3 + 2];
        float m3 = (a + b2 + c) * (1.f / 3.f);
        float va = (a - m3) * (a - m3) + (b2 - m3) * (b2 - m3) + (c - m3) * (c - m3);
        float rs = __builtin_amdgcn_rcpf(__builtin_amdgcn_sqrtf(va * (1.f / 3.f) + 1e-5f));
        xln[n * 3 + 0] = (a - m3) * rs * lnx_w[0] + lnx_b[0];
        xln[n * 3 + 1] = (b2 - m3) * rs * lnx_w[1] + lnx_b[1];
        xln[n * 3 + 2] = (c - m3) * rs * lnx_w[2] + lnx_b[2];
      }
    }
    return;
  }
  int tb = bx - 128;
  const float* src; float* dst; int ld, ntc;
  if (tb < 32)      { src = edg1_w;  dst = e1T; ld = 258; ntc = 8; }
  else if (tb < 64) { src = cor1_w;  dst = c1T; ld = 258; ntc = 8; tb -= 32; }
  else if (tb < 96) { src = node1_w; dst = n1T; ld = 256; ntc = 8; tb -= 64; }
  else              { src = node2_w; dst = n2T; ld = 128; ntc = 4; tb -= 96; }
  const int r0 = (tb / ntc) * 32, c0 = (tb % ntc) * 32;
  const int tx = tid & 31, ty = tid >> 5;
#pragma unroll
  for (int p = 0; p < 4; ++p)
    tile[ty + p * 8][tx] = src[(r0 + ty + p * 8) * ld + c0 + tx];
  __syncthreads();
#pragma unroll
  for (int p = 0; p < 4; ++p)
    dst[(c0 + ty + p * 8) * 128 + r0 + tx] = tile[tx][ty + p * 8];
}

// ---------------- K2: per-node pre-GEMMs + weight repacks ----------------
// w2e/w2c are written in K3's conflict-free LDS order: 16B granule
// G = nt*256 + ks*64 + ch*16 + il holds w2[nt*16+il][ks*32+ch*8 .. +8].
__global__ __launch_bounds__(256, 2) void k2_pre(
    const float* __restrict__ hln,
    const float* __restrict__ e1T, const float* __restrict__ edg1_b,
    const float* __restrict__ c1T, const float* __restrict__ cor1_b,
    const float* __restrict__ edg1_w, const float* __restrict__ cor1_w,
    const float* __restrict__ edg2_w, const float* __restrict__ cor2_w,
    u16* __restrict__ peA, u16* __restrict__ peB,
    u16* __restrict__ pcA, u16* __restrict__ pcB,
    u16* __restrict__ w2e, u16* __restrict__ w2c,
    float* __restrict__ wdwr) {
  const int tid = threadIdx.x;
  const int bx = blockIdx.x;
  if (bx >= 256) {
    const float* src = (bx == 256) ? edg2_w : cor2_w;
    u16* dst = (bx == 256) ? w2e : w2c;
    for (int idx = tid; idx < 16384; idx += 256) {
      int f = idx >> 7, k = idx & 127;
      int nt = f >> 4, il = f & 15, ks = k >> 5, ch = (k >> 3) & 3, e = k & 7;
      dst[(nt * 256 + ks * 64 + ch * 16 + il) * 8 + e] = f2bf(src[idx]);
    }
    const float* w1 = (bx == 256) ? edg1_w : cor1_w;
    float* wvv = wdwr + ((bx == 256) ? 0 : 256);
    if (tid < 128) wvv[tid] = w1[tid * 258 + 256];           // wd (dsq col)
    else           wvv[tid] = w1[(tid - 128) * 258 + 257];   // wr (r0 col)
    return;
  }
  __shared__ __align__(16) float hl[16][132];
  const int arr = bx >> 6;
  const int nb = bx & 63;
  const int n0 = nb * 16;
  for (int idx = tid; idx < 2048; idx += 256) {
    int r = idx >> 7, k = idx & 127;
    hl[r][k] = hln[(n0 + r) * 128 + k];
  }
  __syncthreads();
  const int f = tid & 127, nh = tid >> 7;
  const float* w1T = (arr < 2) ? e1T : c1T;
  const int off = (arr & 1) ? 128 : 0;
  u16* dst = (arr == 0) ? peA : (arr == 1) ? peB : (arr == 2) ? pcA : pcB;
  float bias = 0.f;
  if (arr == 0) bias = edg1_b[f];
  if (arr == 2) bias = cor1_b[f];
  float wreg[128];
#pragma unroll
  for (int t = 0; t < 128; ++t) wreg[t] = w1T[(off + t) * 128 + f];  // coalesced
#pragma unroll 1
  for (int s = 0; s < 8; ++s) {
    int nl = nh * 8 + s;
    float acc = bias;
#pragma unroll
    for (int t = 0; t < 64; ++t) {
      float2 iv = *(const float2*)&hl[nl][t * 2];
      acc += wreg[2 * t] * iv.x + wreg[2 * t + 1] * iv.y;
    }
    dst[(n0 + nl) * 128 + f] = f2bf(acc);
  }
}

// ---------------- K3: fused per-pair edge/coord MLPs (16x16x32 MFMA) -------
// grid 1024: path = bx>>9; per wg: 16 i's x 32 j's, 4 waves; wave w: j=w*8+g.
// REGISTER HISTORY (hard constraint; with MFMA the per-wave budget splits in
// half arch/acc):
//   (256,3): 84 arch -> 1.14 GB scratch spill, 337us           (R4)
//   (256,2) + FULL ks unroll: 350-530 MB spill, 203-278us      (R5/R6)
//   (256,2) + `#pragma unroll 1` ks loop: 88 VGPR, no spill    (R7, 96us)
// R8: cvt_pk + conflict-free LDS: conflicts 4.7M->0, time UNCHANGED (97us)
//     -> conflicts were hidden under the VALU chain. VALUBusy 48% at
//     Occupancy 20% (2 waves/SIMD); limiter = LDS 56.3KB -> 2 blocks/CU.
// R9: drop sagg (-8KB): LDS ~48KB -> 3 blocks/CU -> 3 waves/SIMD; agg merged
//     via global atomics into block-private pre-zeroed pslot (R4/R5-verified
//     path). launch_bounds stays (256,2): compiler floor, HW can run 3.
__global__ __launch_bounds__(256, 2) void k3_pair(
    const float* __restrict__ x, const float* __restrict__ x0,
    const u16* __restrict__ peA, const u16* __restrict__ peB,
    const u16* __restrict__ pcA, const u16* __restrict__ pcB,
    const u16* __restrict__ w2e, const u16* __restrict__ w2c,
    const float* __restrict__ wdwr,
    const float* __restrict__ b2e, const float* __restrict__ b2c,
    const float* __restrict__ edgi_w, const float* __restrict__ edgi_b,
    const float* __restrict__ cor3_w, const float* __restrict__ cor3_b,
    float* __restrict__ cw_t, float* __restrict__ partial) {
  __shared__ __align__(16) u16 sW[2048 * 8];    // 32768 B, granule layout
  __shared__ __align__(16) u16 sA[256 * 8];     // 4096 B, granule layout
  __shared__ __align__(16) u16 sB[32 * 136];    // 8704 B, row-major (bcast reads)
  __shared__ __align__(16) float swd[128];
  __shared__ __align__(16) float swr[128];
  __shared__ float sxi[16][4], sxj[32][4], sx0i[16][4], sx0j[32][4];

  const int tid = threadIdx.x;
  const int bx = blockIdx.x;
  const int path = bx >> 9;
  const int rem = bx & 511;
  const int b = rem >> 7;
  const int ib = (rem >> 3) & 15;
  const int jc = rem & 7;
  const int i0 = ib * 16, j0 = jc * 32;

  const u16* pA = path ? pcA : peA;
  const u16* pB = path ? pcB : peB;
  const u16* w2 = path ? w2c : w2e;
  const float* wdp = wdwr + path * 256;
  const float* b2 = path ? b2c : b2e;
  const float* w3 = path ? cor3_w : edgi_w;
  const float w3b = path ? cor3_b[0] : edgi_b[0];

  float* pslot = partial + ((b * 16 + ib) * 8 + jc) * 2048;

  {
    // sW: already in granule order (K2 pre-transformed) -> linear copy
    const uint4* src = (const uint4*)w2;
    uint4* dst = (uint4*)sW;
    for (int d = tid; d < 2048; d += 256) dst[d] = src[d];
    // sA: granule G = ks*64 + ch*16 + il  <-  src granule il*16 + ks*4 + ch
    {
      const uint4* sa_src = (const uint4*)(pA + (b * 256 + i0) * 128);
      int il = tid & 15, ch = (tid >> 4) & 3, ks = tid >> 6;
      ((uint4*)sA)[tid] = sa_src[il * 16 + ks * 4 + ch];
    }
    const UI* sb_src = (const UI*)(pB + (b * 256 + j0) * 128);
    UI* sb_dst = (UI*)sB;
    for (int d = tid; d < 2048; d += 256) {
      int r = d >> 6, c = d & 63;
      sb_dst[r * 68 + c] = sb_src[d];
    }
    if (tid < 128) swd[tid] = wdp[tid];
    else           swr[tid - 128] = wdp[tid];
    if (tid < 64) {
      int r = tid >> 2, d = tid & 3;
      sxi[r][d]  = (d < 3) ? x[(b * 256 + i0 + r) * 3 + d] : 0.f;
      sx0i[r][d] = (d < 3) ? x0[(b * 256 + i0 + r) * 3 + d] : 0.f;
    }
    if (tid < 128) {
      int r = tid >> 2, d = tid & 3;
      sxj[r][d]  = (d < 3) ? x[(b * 256 + j0 + r) * 3 + d] : 0.f;
      sx0j[r][d] = (d < 3) ? x0[(b * 256 + j0 + r) * 3 + d] : 0.f;
    }
    if (path == 0) {
      for (int d = tid; d < 2048; d += 256) pslot[d] = 0.f;
    }
  }
  __syncthreads();

  const int lane = tid & 63;
  const int w = tid >> 6;
  const int il = lane & 15;   // MFMA row (A) / col (B, C/D)
  const int ch = lane >> 4;   // k-chunk (A/B) / C-row group

  float wv[8], bv[8];
#pragma unroll
  for (int nt = 0; nt < 8; ++nt) {
    wv[nt] = w3[nt * 16 + il];
    bv[nt] = b2[nt * 16 + il];
  }

  float aggv[8][4];
#pragma unroll
  for (int nt = 0; nt < 8; ++nt)
#pragma unroll
    for (int q = 0; q < 4; ++q) aggv[nt][q] = 0.f;

#pragma unroll 1
  for (int g = 0; g < 8; ++g) {
    const int jl = w * 8 + g;  // this wave's j within the block
    float d0 = sxi[il][0] - sxj[jl][0];
    float d1 = sxi[il][1] - sxj[jl][1];
    float d2 = sxi[il][2] - sxj[jl][2];
    const float dsq = d0 * d0 + d1 * d1 + d2 * d2;
    float e0 = sx0i[il][0] - sx0j[jl][0];
    float e1 = sx0i[il][1] - sx0j[jl][1];
    float e2 = sx0i[il][2] - sx0j[jl][2];
    float q2 = e0 * e0 + e1 * e1 + e2 * e2;
    const float r0v = (q2 > 0.f) ? __builtin_amdgcn_sqrtf(q2) : 0.f;

    floatx4 acc[8];
#pragma unroll
    for (int nt = 0; nt < 8; ++nt)
#pragma unroll
      for (int q = 0; q < 4; ++q) acc[nt][q] = 0.f;

#pragma unroll 1
    for (int ks = 0; ks < 4; ++ks) {
      const int f0 = ks * 32 + ch * 8;
      union { float4 v[2]; float a[8]; } wd8, wr8;
      wd8.v[0] = *(const float4*)&swd[f0];
      wd8.v[1] = *(const float4*)&swd[f0 + 4];
      wr8.v[0] = *(const float4*)&swr[f0];
      wr8.v[1] = *(const float4*)&swr[f0 + 4];
      ushort8 a8 = *(const ushort8*)&sA[(ks * 64 + lane) * 8];      // linear
      ushort8 b8 = *(const ushort8*)&sB[jl * 136 + f0];             // bcast
      union { UI w[4]; short8 s; } afu;
#pragma unroll
      for (int e2 = 0; e2 < 4; ++e2) {
        float s0 = fsilu(bf2f((u16)a8[2 * e2]) + bf2f((u16)b8[2 * e2]) +
                         dsq * wd8.a[2 * e2] + r0v * wr8.a[2 * e2]);
        float s1 = fsilu(bf2f((u16)a8[2 * e2 + 1]) + bf2f((u16)b8[2 * e2 + 1]) +
                         dsq * wd8.a[2 * e2 + 1] + r0v * wr8.a[2 * e2 + 1]);
        asm("v_cvt_pk_bf16_f32 %0, %1, %2" : "=v"(afu.w[e2]) : "v"(s0), "v"(s1));
      }
#pragma unroll
      for (int nt = 0; nt < 8; ++nt) {
        short8 bfr = *(const short8*)&sW[(nt * 256 + ks * 64 + lane) * 8];  // linear
        acc[nt] = __builtin_amdgcn_mfma_f32_16x16x32_bf16(afu.s, bfr, acc[nt], 0, 0, 0);
      }
    }
    // epilogue: silu+bias, inner product with w3, 16-lane butterfly reduce
    float p[4] = {0.f, 0.f, 0.f, 0.f};
#pragma unroll
    for (int nt = 0; nt < 8; ++nt) {
#pragma unroll
      for (int q = 0; q < 4; ++q) {
        float s = fsilu(acc[nt][q] + bv[nt]);
        acc[nt][q] = s;
        p[q] += s * wv[nt];
      }
    }
#pragma unroll
    for (int m = 1; m < 16; m <<= 1) {
#pragma unroll
      for (int q = 0; q < 4; ++q) p[q] += __shfl_xor(p[q], m);
    }
    const int jg = j0 + jl;
    if (path == 0) {
#pragma unroll
      for (int q = 0; q < 4; ++q) {
        int ig = i0 + ch * 4 + q;
        float ev = (ig == jg) ? 0.f : fsigmoid(p[q] + w3b);
#pragma unroll
        for (int nt = 0; nt < 8; ++nt) aggv[nt][q] += ev * acc[nt][q];
      }
    } else {
      if (il == 0) {
        float4 v;
        v.x = p[0] + w3b; v.y = p[1] + w3b; v.z = p[2] + w3b; v.w = p[3] + w3b;
        *(float4*)&cw_t[(b * 256 + jg) * 256 + i0 + ch * 4] = v;
      }
    }
  }
  if (path == 0) {
    // merge into block-private pslot (zeroed before the barrier above)
#pragma unroll
    for (int nt = 0; nt < 8; ++nt)
#pragma unroll
      for (int q = 0; q < 4; ++q)
        atomicAdd(&pslot[(ch * 4 + q) * 128 + nt * 16 + il], aggv[nt][q]);
  }
}

// ---------------- K4: node MLP + residual ----------------
__global__ __launch_bounds__(256, 2) void k4_node(
    const float* __restrict__ hln, const float* __restrict__ partial,
    const float* __restrict__ n1T, const float* __restrict__ n1b,
    const float* __restrict__ n2T, const float* __restrict__ n2b,
    float* __restrict__ out) {
  __shared__ __align__(16) float sin_[4][260];
  __shared__ __align__(16) float snu[4][132];
  const int tid = threadIdx.x;
  const int n0 = blockIdx.x * 4;
  for (int idx = tid; idx < 512; idx += 256) {
    int s = idx >> 7, k = idx & 127;
    sin_[s][k] = hln[(n0 + s) * 128 + k];
  }
  for (int idx = tid; idx < 512; idx += 256) {
    int s = idx >> 7, f = idx & 127;
    int n = n0 + s, b = n >> 8, i = n & 255;
    const float* pp = partial + ((b * 16 + (i >> 4)) * 8) * 2048 + (i & 15) * 128 + f;
    float a = 0.f;
#pragma unroll
    for (int j = 0; j < 8; ++j) a += pp[j * 2048];
    sin_[s][128 + f] = a;
  }
  __syncthreads();
  const int f = tid & 127, sh = tid >> 7;
  UI w1r[128];
#pragma unroll
  for (int t = 0; t < 128; ++t) {
    float wa = n1T[(t * 2) * 128 + f];      // coalesced (k-major)
    float wb = n1T[(t * 2 + 1) * 128 + f];
    w1r[t] = (UI)f2bf(wa) | ((UI)f2bf(wb) << 16);
  }
#pragma unroll 1
  for (int t2 = 0; t2 < 2; ++t2) {
    int s = sh * 2 + t2;
    float acc = n1b[f];
#pragma unroll
    for (int t = 0; t < 128; ++t) {
      UI wp = w1r[t];
      float2 iv = *(const float2*)&sin_[s][t * 2];
      acc += iv.x * bf2f((u16)(wp & 0xffffu)) + iv.y * bf2f((u16)(wp >> 16));
    }
    snu[s][f] = fsilu(acc);
  }
  __syncthreads();
  UI w2r[64];
#pragma unroll
  for (int t = 0; t < 64; ++t) {
    float wa = n2T[(t * 2) * 128 + f];
    float wb = n2T[(t * 2 + 1) * 128 + f];
    w2r[t] = (UI)f2bf(wa) | ((UI)f2bf(wb) << 16);
  }
#pragma unroll 1
  for (int t2 = 0; t2 < 2; ++t2) {
    int s = sh * 2 + t2;
    float acc = n2b[f];
#pragma unroll
    for (int t = 0; t < 64; ++t) {
      UI wp = w2r[t];
      float2 iv = *(const float2*)&snu[s][t * 2];
      acc += iv.x * bf2f((u16)(wp & 0xffffu)) + iv.y * bf2f((u16)(wp >> 16));
    }
    out[3072 + (n0 + s) * 128 + f] = sin_[s][f] + acc;  // h_ln + node2(nu)
  }
}

// ---------------- K5: coordinate update ----------------
__global__ __launch_bounds__(256) void k5_x(
    const float* __restrict__ x, const float* __restrict__ xln,
    const float* __restrict__ cw_t, float* __restrict__ out) {
  const int wv = threadIdx.x >> 6, lane = threadIdx.x & 63;
  const int n = blockIdx.x * 4 + wv;
  const int b = n >> 8, i = n & 255;
  const float xi0 = x[n * 3 + 0], xi1 = x[n * 3 + 1], xi2 = x[n * 3 + 2];
  float s0 = 0.f, s1 = 0.f, s2 = 0.f;
#pragma unroll
  for (int t = 0; t < 4; ++t) {
    int j = t * 64 + lane;
    const float* xj = x + (b * 256 + j) * 3;
    float d0 = xi0 - xj[0], d1 = xi1 - xj[1], d2 = xi2 - xj[2];
    float q = d0 * d0 + d1 * d1 + d2 * d2;
    float r = (q > 0.f) ? __builtin_amdgcn_sqrtf(q) : 0.f;
    float cw = cw_t[(b * 256 + j) * 256 + i];
    float sc = cw * __builtin_amdgcn_rcpf(r + 1.f);
    s0 += sc * d0; s1 += sc * d1; s2 += sc * d2;
  }
#pragma unroll
  for (int m = 1; m < 64; m <<= 1) {
    s0 += __shfl_xor(s0, m);
    s1 += __shfl_xor(s1, m);
    s2 += __shfl_xor(s2, m);
  }
  if (lane == 0) {
    out[n * 3 + 0] = xln[n * 3 + 0] + s0;
    out[n * 3 + 1] = xln[n * 3 + 1] + s1;
    out[n * 3 + 2] = xln[n * 3 + 2] + s2;
  }
}

extern "C" void kernel_launch(void* const* d_in, const int* in_sizes, int n_in,
                              void* d_out, int out_size, void* d_ws, size_t ws_size,
                              hipStream_t stream) {
  (void)in_sizes; (void)n_in; (void)out_size; (void)ws_size;
  const float* x      = (const float*)d_in[0];
  const float* h      = (const float*)d_in[1];
  const float* x0     = (const float*)d_in[2];
  const float* lnh_w  = (const float*)d_in[3];
  const float* lnh_b  = (const float*)d_in[4];
  const float* lnx_w  = (const float*)d_in[5];
  const float* lnx_b  = (const float*)d_in[6];
  const float* edg1_w = (const float*)d_in[7];
  const float* edg1_b = (const float*)d_in[8];
  const float* edg2_w = (const float*)d_in[9];
  const float* edg2_b = (const float*)d_in[10];
  const float* edgi_w = (const float*)d_in[11];
  const float* edgi_b = (const float*)d_in[12];
  const float* node1_w= (const float*)d_in[13];
  const float* node1_b= (const float*)d_in[14];
  const float* node2_w= (const float*)d_in[15];
  const float* node2_b= (const float*)d_in[16];
  const float* cor1_w = (const float*)d_in[17];
  const float* cor1_b = (const float*)d_in[18];
  const float* cor2_w = (const float*)d_in[19];
  const float* cor2_b = (const float*)d_in[20];
  const float* cor3_w = (const float*)d_in[21];
  const float* cor3_b = (const float*)d_in[22];

  char* ws = (char*)d_ws;
  float* hln  = (float*)(ws);                 // 1024*128 f32 = 512 KB
  float* xln  = (float*)(ws + 524288);        // 1024*3 f32
  u16* peA    = (u16*)(ws + 536576);          // [1024][128] bf16
  u16* peB    = (u16*)(ws + 798720);
  u16* pcA    = (u16*)(ws + 1060864);
  u16* pcB    = (u16*)(ws + 1323008);
  u16* w2e    = (u16*)(ws + 1585152);         // [2048 granules][8] bf16 = 32 KB
  u16* w2c    = (u16*)(ws + 1619968);
  float* wdwr = (float*)(ws + 1654784);       // [4][128] f32
  float* cw_t = (float*)(ws + 1656832);       // [4][256 j][256 i] f32 = 1 MB
  float* partial = (float*)(ws + 2705408);    // [4][16][8][16][128] f32 = 4 MB
  float* e1T  = (float*)(ws + 6899712);       // [256][128] f32 = 128 KB
  float* c1T  = (float*)(ws + 7030784);       // [256][128] f32
  float* n1T  = (float*)(ws + 7161856);       // [256][128] f32
  float* n2T  = (float*)(ws + 7292928);       // [128][128] f32 = 64 KB
  float* out  = (float*)d_out;

  hipLaunchKernelGGL(k1_ln, dim3(240), dim3(256), 0, stream,
                     h, x, lnh_w, lnh_b, lnx_w, lnx_b,
                     edg1_w, cor1_w, node1_w, node2_w,
                     hln, xln, e1T, c1T, n1T, n2T);
  hipLaunchKernelGGL(k2_pre, dim3(258), dim3(256), 0, stream,
                     hln, e1T, edg1_b, c1T, cor1_b, edg1_w, cor1_w,
                     edg2_w, cor2_w, peA, peB, pcA, pcB, w2e, w2c, wdwr);
  hipLaunchKernelGGL(k3_pair, dim3(1024), dim3(256), 0, stream,
                     x, x0, peA, peB, pcA, pcB, w2e, w2c, wdwr,
                     edg2_b, cor2_b, edgi_w, edgi_b, cor3_w, cor3_b, cw_t, partial);
  hipLaunchKernelGGL(k4_node, dim3(256), dim3(256), 0, stream,
                     hln, partial, n1T, node1_b, n2T, node2_b, out);
  hipLaunchKernelGGL(k5_x, dim3(256), dim3(256), 0, stream,
                     x, xln, cw_t, out);
}

// Round 13
// 212.575 us; speedup vs baseline: 1.2095x; 1.1131x over previous
//
#include <hip/hip_runtime.h>

typedef unsigned int UI;
typedef unsigned short u16;

typedef short short8 __attribute__((ext_vector_type(8)));
typedef float floatx4 __attribute__((ext_vector_type(4)));
typedef unsigned short ushort8 __attribute__((ext_vector_type(8)));

__device__ __forceinline__ float bf2f(u16 u) {
  return __uint_as_float(((UI)u) << 16);
}
__device__ __forceinline__ u16 f2bf(float x) {  // RNE
  UI u = __float_as_uint(x);
  u += 0x7fffu + ((u >> 16) & 1u);
  return (u16)(u >> 16);
}
__device__ __forceinline__ float fsigmoid(float v) {
  float e = __builtin_amdgcn_exp2f(-1.44269504089f * v);
  return __builtin_amdgcn_rcpf(1.0f + e);
}
__device__ __forceinline__ float fsilu(float v) { return v * fsigmoid(v); }

// ---------------- K1: layernorm h/x + weight transposes ----------------
__global__ __launch_bounds__(256) void k1_ln(
    const float* __restrict__ h, const float* __restrict__ x,
    const float* __restrict__ lnh_w, const float* __restrict__ lnh_b,
    const float* __restrict__ lnx_w, const float* __restrict__ lnx_b,
    const float* __restrict__ edg1_w, const float* __restrict__ cor1_w,
    const float* __restrict__ node1_w, const float* __restrict__ node2_w,
    float* __restrict__ hln, float* __restrict__ xln,
    float* __restrict__ e1T, float* __restrict__ c1T,
    float* __restrict__ n1T, float* __restrict__ n2T) {
  __shared__ float tile[32][33];
  const int bx = blockIdx.x, tid = threadIdx.x;
  if (bx < 128) {
    const int wv = tid >> 6, lane = tid & 63;
#pragma unroll 1
    for (int s = 0; s < 2; ++s) {
      const int n = bx * 8 + wv * 2 + s;
      const float* hp = h + n * 128;
      float v0 = hp[lane], v1 = hp[lane + 64];
      float sum = v0 + v1;
#pragma unroll
      for (int m = 1; m < 64; m <<= 1) sum += __shfl_xor(sum, m);
      float mean = sum * 0.0078125f;
      float d0 = v0 - mean, d1 = v1 - mean;
      float vs = d0 * d0 + d1 * d1;
#pragma unroll
      for (int m = 1; m < 64; m <<= 1) vs += __shfl_xor(vs, m);
      float rstd = __builtin_amdgcn_rcpf(__builtin_amdgcn_sqrtf(vs * 0.0078125f + 1e-5f));
      hln[n * 128 + lane]      = d0 * rstd * lnh_w[lane] + lnh_b[lane];
      hln[n * 128 + lane + 64] = d1 * rstd * lnh_w[lane + 64] + lnh_b[lane + 64];
      if (lane == 0) {
        float a = x[n * 3], b2 = x[n * 3 + 1], c = x[n * 3 + 2];
        float m3 = (a + b2 + c) * (1.f / 3.f);
        float va = (a - m3) * (a - m3) + (b2 - m3) * (b2 - m3) + (c - m3) * (c - m3);
        float rs = __builtin_amdgcn_rcpf(__builtin_amdgcn_sqrtf(va * (1.f / 3.f) + 1e-5f));
        xln[n * 3 + 0] = (a - m3) * rs * lnx_w[0] + lnx_b[0];
        xln[n * 3 + 1] = (b2 - m3) * rs * lnx_w[1] + lnx_b[1];
        xln[n * 3 + 2] = (c - m3) * rs * lnx_w[2] + lnx_b[2];
      }
    }
    return;
  }
  int tb = bx - 128;
  const float* src; float* dst; int ld, ntc;
  if (tb < 32)      { src = edg1_w;  dst = e1T; ld = 258; ntc = 8; }
  else if (tb < 64) { src = cor1_w;  dst = c1T; ld = 258; ntc = 8; tb -= 32; }
  else if (tb < 96) { src = node1_w; dst = n1T; ld = 256; ntc = 8; tb -= 64; }
  else              { src = node2_w; dst = n2T; ld = 128; ntc = 4; tb -= 96; }
  const int r0 = (tb / ntc) * 32, c0 = (tb % ntc) * 32;
  const int tx = tid & 31, ty = tid >> 5;
#pragma unroll
  for (int p = 0; p < 4; ++p)
    tile[ty + p * 8][tx] = src[(r0 + ty + p * 8) * ld + c0 + tx];
  __syncthreads();
#pragma unroll
  for (int p = 0; p < 4; ++p)
    dst[(c0 + ty + p * 8) * 128 + r0 + tx] = tile[tx][ty + p * 8];
}

// ---------------- K2: per-node pre-GEMMs + weight repacks ----------------
// w2e/w2c written in K3's conflict-free granule order.
// R10: wreg[128] per-thread array removed (it WAS the whole 128-reg budget ->
// scratch spill, R9 artifact: WRITE 13.9MB vs 1.1MB real output). Streaming
// acc[8] instead: per k-step 1 coalesced w1T load + 8 broadcast LDS reads.
__global__ __launch_bounds__(256, 2) void k2_pre(
    const float* __restrict__ hln,
    const float* __restrict__ e1T, const float* __restrict__ edg1_b,
    const float* __restrict__ c1T, const float* __restrict__ cor1_b,
    const float* __restrict__ edg1_w, const float* __restrict__ cor1_w,
    const float* __restrict__ edg2_w, const float* __restrict__ cor2_w,
    u16* __restrict__ peA, u16* __restrict__ peB,
    u16* __restrict__ pcA, u16* __restrict__ pcB,
    u16* __restrict__ w2e, u16* __restrict__ w2c,
    float* __restrict__ wdwr) {
  const int tid = threadIdx.x;
  const int bx = blockIdx.x;
  if (bx >= 256) {
    const float* src = (bx == 256) ? edg2_w : cor2_w;
    u16* dst = (bx == 256) ? w2e : w2c;
    for (int idx = tid; idx < 16384; idx += 256) {
      int f = idx >> 7, k = idx & 127;
      int nt = f >> 4, il = f & 15, ks = k >> 5, ch = (k >> 3) & 3, e = k & 7;
      dst[(nt * 256 + ks * 64 + ch * 16 + il) * 8 + e] = f2bf(src[idx]);
    }
    const float* w1 = (bx == 256) ? edg1_w : cor1_w;
    float* wvv = wdwr + ((bx == 256) ? 0 : 256);
    if (tid < 128) wvv[tid] = w1[tid * 258 + 256];           // wd (dsq col)
    else           wvv[tid] = w1[(tid - 128) * 258 + 257];   // wr (r0 col)
    return;
  }
  __shared__ __align__(16) float hl[16][132];
  const int arr = bx >> 6;
  const int nb = bx & 63;
  const int n0 = nb * 16;
  for (int idx = tid; idx < 2048; idx += 256) {
    int r = idx >> 7, k = idx & 127;
    hl[r][k] = hln[(n0 + r) * 128 + k];
  }
  __syncthreads();
  const int f = tid & 127, nh = tid >> 7;
  const float* w1T = (arr < 2) ? e1T : c1T;
  const int off = (arr & 1) ? 128 : 0;
  u16* dst = (arr == 0) ? peA : (arr == 1) ? peB : (arr == 2) ? pcA : pcB;
  float bias = 0.f;
  if (arr == 0) bias = edg1_b[f];
  if (arr == 2) bias = cor1_b[f];
  float acc[8];
#pragma unroll
  for (int s = 0; s < 8; ++s) acc[s] = bias;
  const float* wp = w1T + off * 128 + f;
#pragma unroll 4
  for (int t = 0; t < 128; ++t) {
    float wv = wp[t * 128];               // coalesced (k-major)
#pragma unroll
    for (int s = 0; s < 8; ++s)
      acc[s] += wv * hl[nh * 8 + s][t];   // wave-broadcast LDS read
  }
#pragma unroll
  for (int s = 0; s < 8; ++s)
    dst[(n0 + nh * 8 + s) * 128 + f] = f2bf(acc[s]);
}

// ---------------- K3: fused per-pair edge/coord MLPs (16x16x32 MFMA) -------
// grid 1024: path = bx>>9; per wg: 16 i's x 32 j's, 4 waves; wave w: j=w*8+g.
// REGISTER HISTORY (hard constraint; with MFMA the per-wave budget splits in
// half arch/acc):
//   (256,3): 84 arch -> 1.14 GB scratch spill, 337us           (R4)
//   (256,2) + FULL ks unroll: 350-530 MB spill, 203-278us      (R5/R6)
//   (256,2) + `#pragma unroll 1` ks loop: 88 VGPR, no spill    (R7, 96us)
// R8: cvt_pk + conflict-free LDS: conflicts 4.7M->0, time unchanged.
// R9: sagg dropped (-8KB LDS): 48.1KB -> 3 blocks/CU; 74.5us, VALUBusy 64%,
//     VALU-throughput-bound (issue arithmetic matches). Do not touch.
__global__ __launch_bounds__(256, 2) void k3_pair(
    const float* __restrict__ x, const float* __restrict__ x0,
    const u16* __restrict__ peA, const u16* __restrict__ peB,
    const u16* __restrict__ pcA, const u16* __restrict__ pcB,
    const u16* __restrict__ w2e, const u16* __restrict__ w2c,
    const float* __restrict__ wdwr,
    const float* __restrict__ b2e, const float* __restrict__ b2c,
    const float* __restrict__ edgi_w, const float* __restrict__ edgi_b,
    const float* __restrict__ cor3_w, const float* __restrict__ cor3_b,
    float* __restrict__ cw_t, float* __restrict__ partial) {
  __shared__ __align__(16) u16 sW[2048 * 8];    // 32768 B, granule layout
  __shared__ __align__(16) u16 sA[256 * 8];     // 4096 B, granule layout
  __shared__ __align__(16) u16 sB[32 * 136];    // 8704 B, row-major (bcast reads)
  __shared__ __align__(16) float swd[128];
  __shared__ __align__(16) float swr[128];
  __shared__ float sxi[16][4], sxj[32][4], sx0i[16][4], sx0j[32][4];

  const int tid = threadIdx.x;
  const int bx = blockIdx.x;
  const int path = bx >> 9;
  const int rem = bx & 511;
  const int b = rem >> 7;
  const int ib = (rem >> 3) & 15;
  const int jc = rem & 7;
  const int i0 = ib * 16, j0 = jc * 32;

  const u16* pA = path ? pcA : peA;
  const u16* pB = path ? pcB : peB;
  const u16* w2 = path ? w2c : w2e;
  const float* wdp = wdwr + path * 256;
  const float* b2 = path ? b2c : b2e;
  const float* w3 = path ? cor3_w : edgi_w;
  const float w3b = path ? cor3_b[0] : edgi_b[0];

  float* pslot = partial + ((b * 16 + ib) * 8 + jc) * 2048;

  {
    // sW: already in granule order (K2 pre-transformed) -> linear copy
    const uint4* src = (const uint4*)w2;
    uint4* dst = (uint4*)sW;
    for (int d = tid; d < 2048; d += 256) dst[d] = src[d];
    // sA: granule G = ks*64 + ch*16 + il  <-  src granule il*16 + ks*4 + ch
    {
      const uint4* sa_src = (const uint4*)(pA + (b * 256 + i0) * 128);
      int il = tid & 15, ch = (tid >> 4) & 3, ks = tid >> 6;
      ((uint4*)sA)[tid] = sa_src[il * 16 + ks * 4 + ch];
    }
    const UI* sb_src = (const UI*)(pB + (b * 256 + j0) * 128);
    UI* sb_dst = (UI*)sB;
    for (int d = tid; d < 2048; d += 256) {
      int r = d >> 6, c = d & 63;
      sb_dst[r * 68 + c] = sb_src[d];
    }
    if (tid < 128) swd[tid] = wdp[tid];
    else           swr[tid - 128] = wdp[tid];
    if (tid < 64) {
      int r = tid >> 2, d = tid & 3;
      sxi[r][d]  = (d < 3) ? x[(b * 256 + i0 + r) * 3 + d] : 0.f;
      sx0i[r][d] = (d < 3) ? x0[(b * 256 + i0 + r) * 3 + d] : 0.f;
    }
    if (tid < 128) {
      int r = tid >> 2, d = tid & 3;
      sxj[r][d]  = (d < 3) ? x[(b * 256 + j0 + r) * 3 + d] : 0.f;
      sx0j[r][d] = (d < 3) ? x0[(b * 256 + j0 + r) * 3 + d] : 0.f;
    }
    if (path == 0) {
      for (int d = tid; d < 2048; d += 256) pslot[d] = 0.f;
    }
  }
  __syncthreads();

  const int lane = tid & 63;
  const int w = tid >> 6;
  const int il = lane & 15;   // MFMA row (A) / col (B, C/D)
  const int ch = lane >> 4;   // k-chunk (A/B) / C-row group

  float wv[8], bv[8];
#pragma unroll
  for (int nt = 0; nt < 8; ++nt) {
    wv[nt] = w3[nt * 16 + il];
    bv[nt] = b2[nt * 16 + il];
  }

  float aggv[8][4];
#pragma unroll
  for (int nt = 0; nt < 8; ++nt)
#pragma unroll
    for (int q = 0; q < 4; ++q) aggv[nt][q] = 0.f;

#pragma unroll 1
  for (int g = 0; g < 8; ++g) {
    const int jl = w * 8 + g;  // this wave's j within the block
    float d0 = sxi[il][0] - sxj[jl][0];
    float d1 = sxi[il][1] - sxj[jl][1];
    float d2 = sxi[il][2] - sxj[jl][2];
    const float dsq = d0 * d0 + d1 * d1 + d2 * d2;
    float e0 = sx0i[il][0] - sx0j[jl][0];
    float e1 = sx0i[il][1] - sx0j[jl][1];
    float e2 = sx0i[il][2] - sx0j[jl][2];
    float q2 = e0 * e0 + e1 * e1 + e2 * e2;
    const float r0v = (q2 > 0.f) ? __builtin_amdgcn_sqrtf(q2) : 0.f;

    floatx4 acc[8];
#pragma unroll
    for (int nt = 0; nt < 8; ++nt)
#pragma unroll
      for (int q = 0; q < 4; ++q) acc[nt][q] = 0.f;

#pragma unroll 1
    for (int ks = 0; ks < 4; ++ks) {
      const int f0 = ks * 32 + ch * 8;
      union { float4 v[2]; float a[8]; } wd8, wr8;
      wd8.v[0] = *(const float4*)&swd[f0];
      wd8.v[1] = *(const float4*)&swd[f0 + 4];
      wr8.v[0] = *(const float4*)&swr[f0];
      wr8.v[1] = *(const float4*)&swr[f0 + 4];
      ushort8 a8 = *(const ushort8*)&sA[(ks * 64 + lane) * 8];      // linear
      ushort8 b8 = *(const ushort8*)&sB[jl * 136 + f0];             // bcast
      union { UI w[4]; short8 s; } afu;
#pragma unroll
      for (int e2 = 0; e2 < 4; ++e2) {
        float s0 = fsilu(bf2f((u16)a8[2 * e2]) + bf2f((u16)b8[2 * e2]) +
                         dsq * wd8.a[2 * e2] + r0v * wr8.a[2 * e2]);
        float s1 = fsilu(bf2f((u16)a8[2 * e2 + 1]) + bf2f((u16)b8[2 * e2 + 1]) +
                         dsq * wd8.a[2 * e2 + 1] + r0v * wr8.a[2 * e2 + 1]);
        asm("v_cvt_pk_bf16_f32 %0, %1, %2" : "=v"(afu.w[e2]) : "v"(s0), "v"(s1));
      }
#pragma unroll
      for (int nt = 0; nt < 8; ++nt) {
        short8 bfr = *(const short8*)&sW[(nt * 256 + ks * 64 + lane) * 8];  // linear
        acc[nt] = __builtin_amdgcn_mfma_f32_16x16x32_bf16(afu.s, bfr, acc[nt], 0, 0, 0);
      }
    }
    // epilogue: silu+bias, inner product with w3, 16-lane butterfly reduce
    float p[4] = {0.f, 0.f, 0.f, 0.f};
#pragma unroll
    for (int nt = 0; nt < 8; ++nt) {
#pragma unroll
      for (int q = 0; q < 4; ++q) {
        float s = fsilu(acc[nt][q] + bv[nt]);
        acc[nt][q] = s;
        p[q] += s * wv[nt];
      }
    }
#pragma unroll
    for (int m = 1; m < 16; m <<= 1) {
#pragma unroll
      for (int q = 0; q < 4; ++q) p[q] += __shfl_xor(p[q], m);
    }
    const int jg = j0 + jl;
    if (path == 0) {
#pragma unroll
      for (int q = 0; q < 4; ++q) {
        int ig = i0 + ch * 4 + q;
        float ev = (ig == jg) ? 0.f : fsigmoid(p[q] + w3b);
#pragma unroll
        for (int nt = 0; nt < 8; ++nt) aggv[nt][q] += ev * acc[nt][q];
      }
    } else {
      if (il == 0) {
        float4 v;
        v.x = p[0] + w3b; v.y = p[1] + w3b; v.z = p[2] + w3b; v.w = p[3] + w3b;
        *(float4*)&cw_t[(b * 256 + jg) * 256 + i0 + ch * 4] = v;
      }
    }
  }
  if (path == 0) {
    // merge into block-private pslot (zeroed before the barrier above)
#pragma unroll
    for (int nt = 0; nt < 8; ++nt)
#pragma unroll
      for (int q = 0; q < 4; ++q)
        atomicAdd(&pslot[(ch * 4 + q) * 128 + nt * 16 + il], aggv[nt][q]);
  }
}

// ---------------- K4: node MLP + residual ----------------
// R10: w1r[128]/w2r[64] register arrays removed (spill source, R8 artifact:
// FETCH 23.6MB + WRITE 43MB scratch). Streaming acc[2]: per k-step 1
// coalesced f32 weight load + 2 broadcast LDS reads. f32 weights (no f2bf).
__global__ __launch_bounds__(256, 2) void k4_node(
    const float* __restrict__ hln, const float* __restrict__ partial,
    const float* __restrict__ n1T, const float* __restrict__ n1b,
    const float* __restrict__ n2T, const float* __restrict__ n2b,
    float* __restrict__ out) {
  __shared__ __align__(16) float sin_[4][260];
  __shared__ __align__(16) float snu[4][132];
  const int tid = threadIdx.x;
  const int n0 = blockIdx.x * 4;
  for (int idx = tid; idx < 512; idx += 256) {
    int s = idx >> 7, k = idx & 127;
    sin_[s][k] = hln[(n0 + s) * 128 + k];
  }
  for (int idx = tid; idx < 512; idx += 256) {
    int s = idx >> 7, f = idx & 127;
    int n = n0 + s, b = n >> 8, i = n & 255;
    const float* pp = partial + ((b * 16 + (i >> 4)) * 8) * 2048 + (i & 15) * 128 + f;
    float a = 0.f;
#pragma unroll
    for (int j = 0; j < 8; ++j) a += pp[j * 2048];
    sin_[s][128 + f] = a;
  }
  __syncthreads();
  const int f = tid & 127, sh = tid >> 7;
  {
    float acc0 = n1b[f], acc1 = n1b[f];
    const float* wp = n1T + f;
#pragma unroll 4
    for (int t = 0; t < 256; ++t) {
      float wv = wp[t * 128];                 // coalesced (k-major)
      acc0 += wv * sin_[sh * 2 + 0][t];       // wave-broadcast LDS
      acc1 += wv * sin_[sh * 2 + 1][t];
    }
    snu[sh * 2 + 0][f] = fsilu(acc0);
    snu[sh * 2 + 1][f] = fsilu(acc1);
  }
  __syncthreads();
  {
    float acc0 = n2b[f], acc1 = n2b[f];
    const float* wp = n2T + f;
#pragma unroll 4
    for (int t = 0; t < 128; ++t) {
      float wv = wp[t * 128];
      acc0 += wv * snu[sh * 2 + 0][t];
      acc1 += wv * snu[sh * 2 + 1][t];
    }
    out[3072 + (n0 + sh * 2 + 0) * 128 + f] = sin_[sh * 2 + 0][f] + acc0;
    out[3072 + (n0 + sh * 2 + 1) * 128 + f] = sin_[sh * 2 + 1][f] + acc1;
  }
}

// ---------------- K5: coordinate update ----------------
__global__ __launch_bounds__(256) void k5_x(
    const float* __restrict__ x, const float* __restrict__ xln,
    const float* __restrict__ cw_t, float* __restrict__ out) {
  const int wv = threadIdx.x >> 6, lane = threadIdx.x & 63;
  const int n = blockIdx.x * 4 + wv;
  const int b = n >> 8, i = n & 255;
  const float xi0 = x[n * 3 + 0], xi1 = x[n * 3 + 1], xi2 = x[n * 3 + 2];
  float s0 = 0.f, s1 = 0.f, s2 = 0.f;
#pragma unroll
  for (int t = 0; t < 4; ++t) {
    int j = t * 64 + lane;
    const float* xj = x + (b * 256 + j) * 3;
    float d0 = xi0 - xj[0], d1 = xi1 - xj[1], d2 = xi2 - xj[2];
    float q = d0 * d0 + d1 * d1 + d2 * d2;
    float r = (q > 0.f) ? __builtin_amdgcn_sqrtf(q) : 0.f;
    float cw = cw_t[(b * 256 + j) * 256 + i];
    float sc = cw * __builtin_amdgcn_rcpf(r + 1.f);
    s0 += sc * d0; s1 += sc * d1; s2 += sc * d2;
  }
#pragma unroll
  for (int m = 1; m < 64; m <<= 1) {
    s0 += __shfl_xor(s0, m);
    s1 += __shfl_xor(s1, m);
    s2 += __shfl_xor(s2, m);
  }
  if (lane == 0) {
    out[n * 3 + 0] = xln[n * 3 + 0] + s0;
    out[n * 3 + 1] = xln[n * 3 + 1] + s1;
    out[n * 3 + 2] = xln[n * 3 + 2] + s2;
  }
}

extern "C" void kernel_launch(void* const* d_in, const int* in_sizes, int n_in,
                              void* d_out, int out_size, void* d_ws, size_t ws_size,
                              hipStream_t stream) {
  (void)in_sizes; (void)n_in; (void)out_size; (void)ws_size;
  const float* x      = (const float*)d_in[0];
  const float* h      = (const float*)d_in[1];
  const float* x0     = (const float*)d_in[2];
  const float* lnh_w  = (const float*)d_in[3];
  const float* lnh_b  = (const float*)d_in[4];
  const float* lnx_w  = (const float*)d_in[5];
  const float* lnx_b  = (const float*)d_in[6];
  const float* edg1_w = (const float*)d_in[7];
  const float* edg1_b = (const float*)d_in[8];
  const float* edg2_w = (const float*)d_in[9];
  const float* edg2_b = (const float*)d_in[10];
  const float* edgi_w = (const float*)d_in[11];
  const float* edgi_b = (const float*)d_in[12];
  const float* node1_w= (const float*)d_in[13];
  const float* node1_b= (const float*)d_in[14];
  const float* node2_w= (const float*)d_in[15];
  const float* node2_b= (const float*)d_in[16];
  const float* cor1_w = (const float*)d_in[17];
  const float* cor1_b = (const float*)d_in[18];
  const float* cor2_w = (const float*)d_in[19];
  const float* cor2_b = (const float*)d_in[20];
  const float* cor3_w = (const float*)d_in[21];
  const float* cor3_b = (const float*)d_in[22];

  char* ws = (char*)d_ws;
  float* hln  = (float*)(ws);                 // 1024*128 f32 = 512 KB
  float* xln  = (float*)(ws + 524288);        // 1024*3 f32
  u16* peA    = (u16*)(ws + 536576);          // [1024][128] bf16
  u16* peB    = (u16*)(ws + 798720);
  u16* pcA    = (u16*)(ws + 1060864);
  u16* pcB    = (u16*)(ws + 1323008);
  u16* w2e    = (u16*)(ws + 1585152);         // [2048 granules][8] bf16 = 32 KB
  u16* w2c    = (u16*)(ws + 1619968);
  float* wdwr = (float*)(ws + 1654784);       // [4][128] f32
  float* cw_t = (float*)(ws + 1656832);       // [4][256 j][256 i] f32 = 1 MB
  float* partial = (float*)(ws + 2705408);    // [4][16][8][16][128] f32 = 4 MB
  float* e1T  = (float*)(ws + 6899712);       // [256][128] f32 = 128 KB
  float* c1T  = (float*)(ws + 7030784);       // [256][128] f32
  float* n1T  = (float*)(ws + 7161856);       // [256][128] f32
  float* n2T  = (float*)(ws + 7292928);       // [128][128] f32 = 64 KB
  float* out  = (float*)d_out;

  hipLaunchKernelGGL(k1_ln, dim3(240), dim3(256), 0, stream,
                     h, x, lnh_w, lnh_b, lnx_w, lnx_b,
                     edg1_w, cor1_w, node1_w, node2_w,
                     hln, xln, e1T, c1T, n1T, n2T);
  hipLaunchKernelGGL(k2_pre, dim3(258), dim3(256), 0, stream,
                     hln, e1T, edg1_b, c1T, cor1_b, edg1_w, cor1_w,
                     edg2_w, cor2_w, peA, peB, pcA, pcB, w2e, w2c, wdwr);
  hipLaunchKernelGGL(k3_pair, dim3(1024), dim3(256), 0, stream,
                     x, x0, peA, peB, pcA, pcB, w2e, w2c, wdwr,
                     edg2_b, cor2_b, edgi_w, edgi_b, cor3_w, cor3_b, cw_t, partial);
  hipLaunchKernelGGL(k4_node, dim3(256), dim3(256), 0, stream,
                     hln, partial, n1T, node1_b, n2T, node2_b, out);
  hipLaunchKernelGGL(k5_x, dim3(256), dim3(256), 0, stream,
                     x, xln, cw_t, out);
}